// Round 11
// baseline (373.566 us; speedup 1.0000x reference)
//
#include <hip/hip_runtime.h>
#include <hip/hip_bf16.h>

#define N_NODES 50000
#define E_EDGES 600000
#define F_IN    256
#define HC1     128   // 4 heads * 32
#define F_OUT   64
#define SCAN_BLOCKS 49   // ceil(N_NODES / 1024)

typedef __bf16 bf16x8 __attribute__((ext_vector_type(8)));
typedef __bf16 bf16x4 __attribute__((ext_vector_type(4)));
typedef float  f32x4  __attribute__((ext_vector_type(4)));

// -------------------- CSR build --------------------

__global__ void hist_kernel(const int* __restrict__ ei, int* __restrict__ count) {
    int i = blockIdx.x * blockDim.x + threadIdx.x;
    const int total = E_EDGES + N_NODES;
    if (i >= total) return;
    int d = (i < E_EDGES) ? ei[E_EDGES + i] : (i - E_EDGES);
    atomicAdd(&count[d], 1);
}

// hierarchical scan, phase 1: block-local exclusive scan + block totals.
__global__ __launch_bounds__(1024) void scan1_kernel(const int* __restrict__ count,
                                                     int* __restrict__ row_ptr,
                                                     int* __restrict__ bsum) {
    __shared__ int wsum[16];
    int tid = threadIdx.x, lane = tid & 63, w = tid >> 6;
    int i = blockIdx.x * 1024 + tid;
    int v = (i < N_NODES) ? count[i] : 0;
    int s = v;
    #pragma unroll
    for (int d = 1; d < 64; d <<= 1) {
        int t = __shfl_up(s, d);
        if (lane >= d) s += t;
    }
    if (lane == 63) wsum[w] = s;
    __syncthreads();
    if (tid < 16) {
        int t = wsum[tid];
        #pragma unroll
        for (int d = 1; d < 16; d <<= 1) {
            int u = __shfl_up(t, d);
            if (tid >= d) t += u;
        }
        wsum[tid] = t;
    }
    __syncthreads();
    int excl = (w ? wsum[w - 1] : 0) + s - v;
    if (i < N_NODES) row_ptr[i] = excl;
    if (tid == 0) bsum[blockIdx.x] = wsum[15];
}

// phase 2: one wave scans the 49 block totals (exclusive); writes grand total.
__global__ void scan2_kernel(int* __restrict__ bsum, int* __restrict__ row_ptr) {
    int lane = threadIdx.x;   // 64 threads
    int v = (lane < SCAN_BLOCKS) ? bsum[lane] : 0;
    int s = v;
    #pragma unroll
    for (int d = 1; d < 64; d <<= 1) {
        int t = __shfl_up(s, d);
        if (lane >= d) s += t;
    }
    if (lane < SCAN_BLOCKS) bsum[lane] = s - v;
    if (lane == 63) row_ptr[N_NODES] = s;
}

// phase 3: add block offsets; init cursor.
__global__ __launch_bounds__(1024) void scan3_kernel(int* __restrict__ row_ptr,
                                                     const int* __restrict__ bsum,
                                                     int* __restrict__ cursor) {
    int i = blockIdx.x * 1024 + threadIdx.x;
    if (i >= N_NODES) return;
    int v = row_ptr[i] + bsum[blockIdx.x];
    row_ptr[i] = v;
    cursor[i] = v;
}

__global__ void scatter_kernel(const int* __restrict__ ei, int* __restrict__ cursor,
                               int* __restrict__ esrc, int* __restrict__ edst) {
    int i = blockIdx.x * blockDim.x + threadIdx.x;
    const int total = E_EDGES + N_NODES;
    if (i >= total) return;
    int s, d;
    if (i < E_EDGES) { s = ei[i]; d = ei[E_EDGES + i]; }
    else             { s = d = i - E_EDGES; }
    int pos = atomicAdd(&cursor[d], 1);
    esrc[pos] = s;
    edst[pos] = d;
}

// -------------------- W pre-pack into MFMA B-fragment order (bf16 hi/lo) ------

template<int KDIM, int NC>
__global__ void pack_w_kernel(const float* __restrict__ W,
                              __bf16* __restrict__ hi, __bf16* __restrict__ lo) {
    constexpr int KT  = KDIM / 32;
    constexpr int LKT = (KT == 8) ? 3 : 2;
    int tid = blockIdx.x * blockDim.x + threadIdx.x;
    if (tid >= KDIM * NC) return;
    int j  = tid & 7;
    int l  = (tid >> 3) & 63;
    int kt = (tid >> 9) & (KT - 1);
    int ct = tid >> (9 + LKT);
    int k   = kt * 32 + (l >> 4) * 8 + j;
    int col = ct * 16 + (l & 15);
    float v = W[k * NC + col];
    __bf16 h = (__bf16)v;
    hi[tid] = h;
    lo[tid] = (__bf16)(v - (float)h);
}

// -------------------- persistent split-bf16 MFMA GEMM, B in LDS ---------------
// Block stages its B col-half (fragment-ordered) into LDS ONCE; 16 waves then
// loop over 16-row tiles, reading A direct from global (fp32, 128B segments)
// with 1-kt register prefetch, converting to bf16 hi/lo in-reg. B reads are
// lane-contiguous ds_read_b128 (conflict-free). al_s/al_d fused in epilogue.

template<int KDIM, int NC, bool CBF16, int CGROUPS>
__global__ __launch_bounds__(1024, 4) void gemm_persist_kernel(
        const float* __restrict__ A,
        const __bf16* __restrict__ Whi, const __bf16* __restrict__ Wlo,
        const float* __restrict__ a_s, const float* __restrict__ a_d,
        void* __restrict__ Cout, float* __restrict__ als, float* __restrict__ ald) {
    constexpr int KT  = KDIM / 32;
    constexpr int CT  = NC / 16;
    constexpr int CTW = CT / CGROUPS;          // col tiles handled per block
    constexpr int NH  = KDIM * NC / CGROUPS;   // staged bf16 elems per array
    constexpr int NTILES = N_NODES / 16;       // 3125 (exact)
    __shared__ __bf16 Bh[NH];
    __shared__ __bf16 Bl[NH];

    int tid = threadIdx.x;
    int cg  = (CGROUPS == 2) ? (blockIdx.x & 1) : 0;
    int c0  = cg * CTW;

    // stage B half: fragment-ordered in global -> linear LDS copy (coalesced)
    const __bf16* wh = Whi + (size_t)c0 * KT * 512;
    const __bf16* wl = Wlo + (size_t)c0 * KT * 512;
    for (int i = tid; i < NH / 8; i += 1024) {
        ((bf16x8*)Bh)[i] = ((const bf16x8*)wh)[i];
        ((bf16x8*)Bl)[i] = ((const bf16x8*)wl)[i];
    }
    __syncthreads();

    int w = tid >> 6, l = tid & 63;
    int koff = (l >> 4) * 8;
    int ccol = l & 15;
    int tb = (CGROUPS == 2) ? (int)(blockIdx.x >> 1) : (int)blockIdx.x;
    int nb = (CGROUPS == 2) ? (int)(gridDim.x >> 1) : (int)gridDim.x;

    float as_c[CTW], ad_c[CTW];
    #pragma unroll
    for (int c = 0; c < CTW; ++c) {
        as_c[c] = a_s[(c0 + c) * 16 + ccol];
        ad_c[c] = a_d[(c0 + c) * 16 + ccol];
    }

    for (int tile = tb * 16 + w; tile < NTILES; tile += nb * 16) {
        int r0 = tile * 16;
        const float* ap = A + (size_t)(r0 + (l & 15)) * KDIM + koff;

        f32x4 acc[CTW];
        #pragma unroll
        for (int c = 0; c < CTW; ++c) acc[c] = (f32x4){0.f, 0.f, 0.f, 0.f};

        float4 a0 = *(const float4*)ap;
        float4 a1 = *(const float4*)(ap + 4);
        #pragma unroll
        for (int kt = 0; kt < KT; ++kt) {
            float4 n0, n1;
            if (kt + 1 < KT) {
                n0 = *(const float4*)(ap + (kt + 1) * 32);
                n1 = *(const float4*)(ap + (kt + 1) * 32 + 4);
            }
            float xv[8] = {a0.x, a0.y, a0.z, a0.w, a1.x, a1.y, a1.z, a1.w};
            bf16x8 ahi, alo;
            #pragma unroll
            for (int j = 0; j < 8; ++j) {
                __bf16 h = (__bf16)xv[j];
                ahi[j] = h;
                alo[j] = (__bf16)(xv[j] - (float)h);
            }
            #pragma unroll
            for (int c = 0; c < CTW; ++c) {
                int bb = ((c * KT + kt) * 64 + l) * 8;
                bf16x8 bh = *(const bf16x8*)&Bh[bb];
                bf16x8 bl = *(const bf16x8*)&Bl[bb];
                acc[c] = __builtin_amdgcn_mfma_f32_16x16x32_bf16(ahi, bh, acc[c], 0, 0, 0);
                acc[c] = __builtin_amdgcn_mfma_f32_16x16x32_bf16(ahi, bl, acc[c], 0, 0, 0);
                acc[c] = __builtin_amdgcn_mfma_f32_16x16x32_bf16(alo, bh, acc[c], 0, 0, 0);
            }
            a0 = n0; a1 = n1;
        }

        int crow0 = r0 + (l >> 4) * 4;

        // C store (N_NODES % 16 == 0: no guards needed)
        #pragma unroll
        for (int c = 0; c < CTW; ++c) {
            #pragma unroll
            for (int r = 0; r < 4; ++r) {
                int row = crow0 + r;
                if constexpr (CBF16)
                    ((__bf16*)Cout)[(size_t)row * NC + (c0 + c) * 16 + ccol] = (__bf16)acc[c][r];
                else
                    ((float*)Cout)[(size_t)row * NC + (c0 + c) * 16 + ccol] = acc[c][r];
            }
        }

        // fused attention scalars (wave-local reductions over 16 cols)
        #pragma unroll
        for (int r = 0; r < 4; ++r) {
            int row = crow0 + r;
            if constexpr (NC == 128) {
                // CTW=4: this block's col-half holds 2 whole heads
                #pragma unroll
                for (int hl = 0; hl < 2; ++hl) {
                    int h = cg * 2 + hl;
                    float vs = acc[2 * hl][r] * as_c[2 * hl] + acc[2 * hl + 1][r] * as_c[2 * hl + 1];
                    float vd = acc[2 * hl][r] * ad_c[2 * hl] + acc[2 * hl + 1][r] * ad_c[2 * hl + 1];
                    #pragma unroll
                    for (int d = 1; d < 16; d <<= 1) {
                        vs += __shfl_xor(vs, d);
                        vd += __shfl_xor(vd, d);
                    }
                    if (ccol == 0) { als[row * 4 + h] = vs; ald[row * 4 + h] = vd; }
                }
            } else {
                float vs = 0.f, vd = 0.f;
                #pragma unroll
                for (int c = 0; c < CTW; ++c) { vs += acc[c][r] * as_c[c]; vd += acc[c][r] * ad_c[c]; }
                #pragma unroll
                for (int d = 1; d < 16; d <<= 1) {
                    vs += __shfl_xor(vs, d);
                    vd += __shfl_xor(vd, d);
                }
                if (ccol == 0) { als[row] = vs; ald[row] = vd; }
            }
        }
    }
}

__device__ __forceinline__ float lrelu(float x) { return x > 0.f ? x : 0.2f * x; }
__device__ __forceinline__ float bfhi(unsigned v) { return __uint_as_float(v & 0xffff0000u); }
__device__ __forceinline__ float bflo(unsigned v) { return __uint_as_float(v << 16); }

// -------------------- per-edge attention weights (unnormalized) --------------------

__global__ __launch_bounds__(256) void p1_kernel(const int* __restrict__ esrc,
                                                 const int* __restrict__ edst,
                                                 const float* __restrict__ als,
                                                 const float* __restrict__ ald,
                                                 float* __restrict__ p1) {
    int j = blockIdx.x * 256 + threadIdx.x;
    if (j >= E_EDGES + N_NODES) return;
    int s = esrc[j], d = edst[j];
    float4 as = *(const float4*)&als[s * 4];
    float4 ad = *(const float4*)&ald[d * 4];
    float4 p;
    p.x = __expf(lrelu(as.x + ad.x));
    p.y = __expf(lrelu(as.y + ad.y));
    p.z = __expf(lrelu(as.z + ad.z));
    p.w = __expf(lrelu(as.w + ad.w));
    *(float4*)&p1[(size_t)j * 4] = p;
}

__global__ __launch_bounds__(256) void p2_kernel(const int* __restrict__ esrc,
                                                 const int* __restrict__ edst,
                                                 const float* __restrict__ als,
                                                 const float* __restrict__ ald,
                                                 float* __restrict__ p2) {
    int j = blockIdx.x * 256 + threadIdx.x;
    if (j >= E_EDGES + N_NODES) return;
    p2[j] = __expf(lrelu(als[esrc[j]] + ald[edst[j]]));
}

// -------------------- single-pass aggregation (streamed p) --------------------

// layer 1: 1 wave per dst. 4 groups x 16 lanes; group g handles edge j0+g;
// lane li covers cols li*8..li*8+7 (head li>>2) via one 16B load.
__global__ __launch_bounds__(256) void aggr1_kernel(const int* __restrict__ row_ptr,
                                                    const int* __restrict__ esrc,
                                                    const float* __restrict__ p1,
                                                    const __bf16* __restrict__ h1b,
                                                    const float* __restrict__ b1,
                                                    float* __restrict__ h2out) {
    int wid = blockIdx.x * 4 + (threadIdx.x >> 6);
    int lane = threadIdx.x & 63;
    int grp = lane >> 4, li = lane & 15;
    int hh = li >> 2;                       // head of this lane's 8 cols
    int beg = row_ptr[wid], end = row_ptr[wid + 1];
    float acc[8] = {0,0,0,0,0,0,0,0};
    float S = 0.f;
    for (int j0 = beg; j0 < end; j0 += 4) {
        int j = j0 + grp;
        bool valid = (j < end);
        int s = valid ? esrc[j] : 0;
        float p = valid ? p1[(size_t)j * 4 + hh] : 0.f;   // streamed, CSR-contiguous
        uint4 v = *(const uint4*)(h1b + (size_t)s * HC1 + li * 8);
        acc[0] += p * bflo(v.x); acc[1] += p * bfhi(v.x);
        acc[2] += p * bflo(v.y); acc[3] += p * bfhi(v.y);
        acc[4] += p * bflo(v.z); acc[5] += p * bfhi(v.z);
        acc[6] += p * bflo(v.w); acc[7] += p * bfhi(v.w);
        S += p;
    }
    // reduce across the 4 groups (lane bits 4,5)
    #pragma unroll
    for (int d = 16; d < 64; d <<= 1) {
        #pragma unroll
        for (int c = 0; c < 8; ++c) acc[c] += __shfl_xor(acc[c], d);
        S += __shfl_xor(S, d);
    }
    if (grp == 0) {
        float inv = 1.f / S;
        const float* bp = b1 + li * 8;
        float4 o0, o1;
        o0.x = lrelu(acc[0] * inv + bp[0]);
        o0.y = lrelu(acc[1] * inv + bp[1]);
        o0.z = lrelu(acc[2] * inv + bp[2]);
        o0.w = lrelu(acc[3] * inv + bp[3]);
        o1.x = lrelu(acc[4] * inv + bp[4]);
        o1.y = lrelu(acc[5] * inv + bp[5]);
        o1.z = lrelu(acc[6] * inv + bp[6]);
        o1.w = lrelu(acc[7] * inv + bp[7]);
        float* orow = h2out + (size_t)wid * HC1 + li * 8;
        *(float4*)orow = o0;
        *(float4*)(orow + 4) = o1;
    }
}

// layer 2: 1 wave per dst; 4 groups x 16 lanes; lane li covers cols li*4..li*4+3.
__global__ __launch_bounds__(256) void aggr2_kernel(const int* __restrict__ row_ptr,
                                                    const int* __restrict__ esrc,
                                                    const float* __restrict__ p2,
                                                    const float* __restrict__ g,
                                                    const float* __restrict__ b2,
                                                    float* __restrict__ out) {
    int wid = blockIdx.x * 4 + (threadIdx.x >> 6);
    int lane = threadIdx.x & 63;
    int grp = lane >> 4, li = lane & 15;
    int beg = row_ptr[wid], end = row_ptr[wid + 1];
    float a0 = 0.f, a1 = 0.f, a2 = 0.f, a3 = 0.f, S = 0.f;
    for (int j0 = beg; j0 < end; j0 += 4) {
        int j = j0 + grp;
        bool valid = (j < end);
        int s = valid ? esrc[j] : 0;
        float p = valid ? p2[j] : 0.f;
        float4 gv = *(const float4*)(g + (size_t)s * F_OUT + li * 4);
        a0 += p * gv.x; a1 += p * gv.y; a2 += p * gv.z; a3 += p * gv.w;
        S += p;
    }
    #pragma unroll
    for (int d = 16; d < 64; d <<= 1) {
        a0 += __shfl_xor(a0, d); a1 += __shfl_xor(a1, d);
        a2 += __shfl_xor(a2, d); a3 += __shfl_xor(a3, d);
        S += __shfl_xor(S, d);
    }
    if (grp == 0) {
        float inv = 1.f / S;
        const float* bp = b2 + li * 4;
        float4 o;
        o.x = a0 * inv + bp[0];
        o.y = a1 * inv + bp[1];
        o.z = a2 * inv + bp[2];
        o.w = a3 * inv + bp[3];
        *(float4*)(out + (size_t)wid * F_OUT + li * 4) = o;
    }
}

// -------------------- launch --------------------

extern "C" void kernel_launch(void* const* d_in, const int* in_sizes, int n_in,
                              void* d_out, int out_size, void* d_ws, size_t ws_size,
                              hipStream_t stream) {
    const float* x      = (const float*)d_in[0];
    const int*   ei     = (const int*)  d_in[1];
    const float* W1     = (const float*)d_in[2];
    const float* a_src1 = (const float*)d_in[3];
    const float* a_dst1 = (const float*)d_in[4];
    const float* b1     = (const float*)d_in[5];
    const float* W2     = (const float*)d_in[6];
    const float* a_src2 = (const float*)d_in[7];
    const float* a_dst2 = (const float*)d_in[8];
    const float* b2     = (const float*)d_in[9];
    float* out = (float*)d_out;
    char* ws = (char*)d_ws;

    // workspace layout (bytes)
    __bf16* h1b  = (__bf16*)(ws + 0);           // N*128*2 = 12,800,000
    float* h2    = (float*)(ws + 12800000);     // N*128*4 = 25,600,000
    float* g     = (float*)(ws + 38400000);     // N*64*4 = 12,800,000
    float* als1  = (float*)(ws + 51200000);     // N*4*4 = 800,000
    float* ald1  = (float*)(ws + 52000000);     // 800,000
    float* als2  = (float*)(ws + 52800000);     // 200,000
    float* ald2  = (float*)(ws + 53000000);     // 200,000
    int*   rowp  = (int*)  (ws + 53200000);     // (N+1)*4
    int*   cursor= (int*)  (ws + 53400064);     // N*4
    int*   esrc  = (int*)  (ws + 53600064);     // (E+N)*4 = 2,600,000
    __bf16* whi1 = (__bf16*)(ws + 56200064);    // 65,536
    __bf16* wlo1 = (__bf16*)(ws + 56265600);    // 65,536
    __bf16* whi2 = (__bf16*)(ws + 56331136);    // 16,384
    __bf16* wlo2 = (__bf16*)(ws + 56347520);    // 16,384
    int*   bsum  = (int*)  (ws + 56363904);     // 196 B
    int*   edst  = (int*)  (ws + 56364160);     // (E+N)*4 = 2,600,000 (end 58,964,160)
    // recycled regions:
    float* p1 = g;                // 10.4MB <= 12.8MB; consumed by aggr1 before gemm2 writes g
    float* p2 = (float*)h1b;      // 2.6MB; h1b dead after aggr1

    const int TOT = E_EDGES + N_NODES;
    const int eb = (TOT + 255) / 256;

    hipMemsetAsync(cursor, 0, N_NODES * sizeof(int), stream);
    hist_kernel<<<eb, 256, 0, stream>>>(ei, cursor);
    scan1_kernel<<<SCAN_BLOCKS, 1024, 0, stream>>>(cursor, rowp, bsum);
    scan2_kernel<<<1, 64, 0, stream>>>(bsum, rowp);
    scan3_kernel<<<SCAN_BLOCKS, 1024, 0, stream>>>(rowp, bsum, cursor);
    scatter_kernel<<<eb, 256, 0, stream>>>(ei, cursor, esrc, edst);

    pack_w_kernel<F_IN, HC1><<<(F_IN * HC1 + 255) / 256, 256, 0, stream>>>(W1, whi1, wlo1);
    pack_w_kernel<HC1, F_OUT><<<(HC1 * F_OUT + 255) / 256, 256, 0, stream>>>(W2, whi2, wlo2);

    // gemm1: 196 tile-groups x 2 col-halves; 16 waves/block, B-half (64KB) in LDS
    gemm_persist_kernel<F_IN, HC1, true, 2><<<392, 1024, 0, stream>>>(
        x, whi1, wlo1, a_src1, a_dst1, h1b, als1, ald1);
    p1_kernel<<<eb, 256, 0, stream>>>(esrc, edst, als1, ald1, p1);
    aggr1_kernel<<<N_NODES / 4, 256, 0, stream>>>(rowp, esrc, p1, h1b, b1, h2);

    // gemm2: full B (32KB) in LDS
    gemm_persist_kernel<HC1, F_OUT, false, 1><<<196, 1024, 0, stream>>>(
        h2, whi2, wlo2, a_src2, a_dst2, g, als2, ald2);
    p2_kernel<<<eb, 256, 0, stream>>>(esrc, edst, als2, ald2, p2);
    aggr2_kernel<<<N_NODES / 4, 256, 0, stream>>>(rowp, esrc, p2, g, b2, out);
}

// Round 12
// 339.253 us; speedup vs baseline: 1.1011x; 1.1011x over previous
//
#include <hip/hip_runtime.h>
#include <hip/hip_bf16.h>

#define N_NODES 50000
#define E_EDGES 600000
#define F_IN    256
#define HC1     128   // 4 heads * 32
#define F_OUT   64
#define SCAN_BLOCKS 49   // ceil(N_NODES / 1024)

typedef __bf16 bf16x8 __attribute__((ext_vector_type(8)));
typedef __bf16 bf16x4 __attribute__((ext_vector_type(4)));
typedef float  f32x4  __attribute__((ext_vector_type(4)));

// -------------------- CSR build --------------------

__global__ void hist_kernel(const int* __restrict__ ei, int* __restrict__ count) {
    int i = blockIdx.x * blockDim.x + threadIdx.x;
    const int total = E_EDGES + N_NODES;
    if (i >= total) return;
    int d = (i < E_EDGES) ? ei[E_EDGES + i] : (i - E_EDGES);
    atomicAdd(&count[d], 1);
}

// hierarchical scan, phase 1: block-local exclusive scan + block totals.
__global__ __launch_bounds__(1024) void scan1_kernel(const int* __restrict__ count,
                                                     int* __restrict__ row_ptr,
                                                     int* __restrict__ bsum) {
    __shared__ int wsum[16];
    int tid = threadIdx.x, lane = tid & 63, w = tid >> 6;
    int i = blockIdx.x * 1024 + tid;
    int v = (i < N_NODES) ? count[i] : 0;
    int s = v;
    #pragma unroll
    for (int d = 1; d < 64; d <<= 1) {
        int t = __shfl_up(s, d);
        if (lane >= d) s += t;
    }
    if (lane == 63) wsum[w] = s;
    __syncthreads();
    if (tid < 16) {
        int t = wsum[tid];
        #pragma unroll
        for (int d = 1; d < 16; d <<= 1) {
            int u = __shfl_up(t, d);
            if (tid >= d) t += u;
        }
        wsum[tid] = t;
    }
    __syncthreads();
    int excl = (w ? wsum[w - 1] : 0) + s - v;
    if (i < N_NODES) row_ptr[i] = excl;
    if (tid == 0) bsum[blockIdx.x] = wsum[15];
}

// phase 2: one wave scans the 49 block totals (exclusive); writes grand total.
__global__ void scan2_kernel(int* __restrict__ bsum, int* __restrict__ row_ptr) {
    int lane = threadIdx.x;   // 64 threads
    int v = (lane < SCAN_BLOCKS) ? bsum[lane] : 0;
    int s = v;
    #pragma unroll
    for (int d = 1; d < 64; d <<= 1) {
        int t = __shfl_up(s, d);
        if (lane >= d) s += t;
    }
    if (lane < SCAN_BLOCKS) bsum[lane] = s - v;
    if (lane == 63) row_ptr[N_NODES] = s;
}

// phase 3: add block offsets; init cursor.
__global__ __launch_bounds__(1024) void scan3_kernel(int* __restrict__ row_ptr,
                                                     const int* __restrict__ bsum,
                                                     int* __restrict__ cursor) {
    int i = blockIdx.x * 1024 + threadIdx.x;
    if (i >= N_NODES) return;
    int v = row_ptr[i] + bsum[blockIdx.x];
    row_ptr[i] = v;
    cursor[i] = v;
}

__global__ void scatter_kernel(const int* __restrict__ ei, int* __restrict__ cursor,
                               int* __restrict__ esrc, int* __restrict__ edst) {
    int i = blockIdx.x * blockDim.x + threadIdx.x;
    const int total = E_EDGES + N_NODES;
    if (i >= total) return;
    int s, d;
    if (i < E_EDGES) { s = ei[i]; d = ei[E_EDGES + i]; }
    else             { s = d = i - E_EDGES; }
    int pos = atomicAdd(&cursor[d], 1);
    esrc[pos] = s;
    edst[pos] = d;
}

// -------------------- W pre-pack into MFMA B-fragment order (bf16 hi/lo) ------

template<int KDIM, int NC>
__global__ void pack_w_kernel(const float* __restrict__ W,
                              __bf16* __restrict__ hi, __bf16* __restrict__ lo) {
    constexpr int KT  = KDIM / 32;
    constexpr int LKT = (KT == 8) ? 3 : 2;
    int tid = blockIdx.x * blockDim.x + threadIdx.x;
    if (tid >= KDIM * NC) return;
    int j  = tid & 7;
    int l  = (tid >> 3) & 63;
    int kt = (tid >> 9) & (KT - 1);
    int ct = tid >> (9 + LKT);
    int k   = kt * 32 + (l >> 4) * 8 + j;
    int col = ct * 16 + (l & 15);
    float v = W[k * NC + col];
    __bf16 h = (__bf16)v;
    hi[tid] = h;
    lo[tid] = (__bf16)(v - (float)h);
}

// -------------------- persistent split-bf16 MFMA GEMM, B in LDS ---------------
// Block stages its B col-half (fragment-ordered) into LDS ONCE; 16 waves then
// loop over 16-row tiles, reading A direct from global (fp32, 128B segments)
// with 1-kt register prefetch, converting to bf16 hi/lo in-reg. B reads are
// lane-contiguous ds_read_b128 (conflict-free). al_s/al_d fused in epilogue.
// NOTE: no min-waves in launch_bounds — (1024,4) capped VGPR at 64 and spilled
// the hot loop to scratch (R11: 333MB scratch writes). Default cap is 128.

template<int KDIM, int NC, bool CBF16, int CGROUPS>
__global__ __launch_bounds__(1024) void gemm_persist_kernel(
        const float* __restrict__ A,
        const __bf16* __restrict__ Whi, const __bf16* __restrict__ Wlo,
        const float* __restrict__ a_s, const float* __restrict__ a_d,
        void* __restrict__ Cout, float* __restrict__ als, float* __restrict__ ald) {
    constexpr int KT  = KDIM / 32;
    constexpr int CT  = NC / 16;
    constexpr int CTW = CT / CGROUPS;          // col tiles handled per block
    constexpr int NH  = KDIM * NC / CGROUPS;   // staged bf16 elems per array
    constexpr int NTILES = N_NODES / 16;       // 3125 (exact)
    __shared__ __bf16 Bh[NH];
    __shared__ __bf16 Bl[NH];

    int tid = threadIdx.x;
    int cg  = (CGROUPS == 2) ? (blockIdx.x & 1) : 0;
    int c0  = cg * CTW;

    // stage B half: fragment-ordered in global -> linear LDS copy (coalesced)
    const __bf16* wh = Whi + (size_t)c0 * KT * 512;
    const __bf16* wl = Wlo + (size_t)c0 * KT * 512;
    for (int i = tid; i < NH / 8; i += 1024) {
        ((bf16x8*)Bh)[i] = ((const bf16x8*)wh)[i];
        ((bf16x8*)Bl)[i] = ((const bf16x8*)wl)[i];
    }
    __syncthreads();

    int w = tid >> 6, l = tid & 63;
    int koff = (l >> 4) * 8;
    int ccol = l & 15;
    int tb = (CGROUPS == 2) ? (int)(blockIdx.x >> 1) : (int)blockIdx.x;
    int nb = (CGROUPS == 2) ? (int)(gridDim.x >> 1) : (int)gridDim.x;

    float as_c[CTW], ad_c[CTW];
    #pragma unroll
    for (int c = 0; c < CTW; ++c) {
        as_c[c] = a_s[(c0 + c) * 16 + ccol];
        ad_c[c] = a_d[(c0 + c) * 16 + ccol];
    }

    for (int tile = tb * 16 + w; tile < NTILES; tile += nb * 16) {
        int r0 = tile * 16;
        const float* ap = A + (size_t)(r0 + (l & 15)) * KDIM + koff;

        f32x4 acc[CTW];
        #pragma unroll
        for (int c = 0; c < CTW; ++c) acc[c] = (f32x4){0.f, 0.f, 0.f, 0.f};

        float4 a0 = *(const float4*)ap;
        float4 a1 = *(const float4*)(ap + 4);
        #pragma unroll
        for (int kt = 0; kt < KT; ++kt) {
            float4 n0, n1;
            if (kt + 1 < KT) {
                n0 = *(const float4*)(ap + (kt + 1) * 32);
                n1 = *(const float4*)(ap + (kt + 1) * 32 + 4);
            }
            float xv[8] = {a0.x, a0.y, a0.z, a0.w, a1.x, a1.y, a1.z, a1.w};
            bf16x8 ahi, alo;
            #pragma unroll
            for (int j = 0; j < 8; ++j) {
                __bf16 h = (__bf16)xv[j];
                ahi[j] = h;
                alo[j] = (__bf16)(xv[j] - (float)h);
            }
            #pragma unroll
            for (int c = 0; c < CTW; ++c) {
                int bb = ((c * KT + kt) * 64 + l) * 8;
                bf16x8 bh = *(const bf16x8*)&Bh[bb];
                bf16x8 bl = *(const bf16x8*)&Bl[bb];
                acc[c] = __builtin_amdgcn_mfma_f32_16x16x32_bf16(ahi, bh, acc[c], 0, 0, 0);
                acc[c] = __builtin_amdgcn_mfma_f32_16x16x32_bf16(ahi, bl, acc[c], 0, 0, 0);
                acc[c] = __builtin_amdgcn_mfma_f32_16x16x32_bf16(alo, bh, acc[c], 0, 0, 0);
            }
            a0 = n0; a1 = n1;
        }

        int crow0 = r0 + (l >> 4) * 4;

        // C store (N_NODES % 16 == 0: no guards needed)
        #pragma unroll
        for (int c = 0; c < CTW; ++c) {
            #pragma unroll
            for (int r = 0; r < 4; ++r) {
                int row = crow0 + r;
                if constexpr (CBF16)
                    ((__bf16*)Cout)[(size_t)row * NC + (c0 + c) * 16 + ccol] = (__bf16)acc[c][r];
                else
                    ((float*)Cout)[(size_t)row * NC + (c0 + c) * 16 + ccol] = acc[c][r];
            }
        }

        // fused attention scalars (wave-local reductions over 16 cols)
        #pragma unroll
        for (int r = 0; r < 4; ++r) {
            int row = crow0 + r;
            if constexpr (NC == 128) {
                // CTW=4: this block's col-half holds 2 whole heads
                #pragma unroll
                for (int hl = 0; hl < 2; ++hl) {
                    int h = cg * 2 + hl;
                    float vs = acc[2 * hl][r] * as_c[2 * hl] + acc[2 * hl + 1][r] * as_c[2 * hl + 1];
                    float vd = acc[2 * hl][r] * ad_c[2 * hl] + acc[2 * hl + 1][r] * ad_c[2 * hl + 1];
                    #pragma unroll
                    for (int d = 1; d < 16; d <<= 1) {
                        vs += __shfl_xor(vs, d);
                        vd += __shfl_xor(vd, d);
                    }
                    if (ccol == 0) { als[row * 4 + h] = vs; ald[row * 4 + h] = vd; }
                }
            } else {
                float vs = 0.f, vd = 0.f;
                #pragma unroll
                for (int c = 0; c < CTW; ++c) { vs += acc[c][r] * as_c[c]; vd += acc[c][r] * ad_c[c]; }
                #pragma unroll
                for (int d = 1; d < 16; d <<= 1) {
                    vs += __shfl_xor(vs, d);
                    vd += __shfl_xor(vd, d);
                }
                if (ccol == 0) { als[row] = vs; ald[row] = vd; }
            }
        }
    }
}

__device__ __forceinline__ float lrelu(float x) { return x > 0.f ? x : 0.2f * x; }
__device__ __forceinline__ float bfhi(unsigned v) { return __uint_as_float(v & 0xffff0000u); }
__device__ __forceinline__ float bflo(unsigned v) { return __uint_as_float(v << 16); }

// -------------------- per-edge attention weights (unnormalized) --------------------

__global__ __launch_bounds__(256) void p1_kernel(const int* __restrict__ esrc,
                                                 const int* __restrict__ edst,
                                                 const float* __restrict__ als,
                                                 const float* __restrict__ ald,
                                                 float* __restrict__ p1) {
    int j = blockIdx.x * 256 + threadIdx.x;
    if (j >= E_EDGES + N_NODES) return;
    int s = esrc[j], d = edst[j];
    float4 as = *(const float4*)&als[s * 4];
    float4 ad = *(const float4*)&ald[d * 4];
    float4 p;
    p.x = __expf(lrelu(as.x + ad.x));
    p.y = __expf(lrelu(as.y + ad.y));
    p.z = __expf(lrelu(as.z + ad.z));
    p.w = __expf(lrelu(as.w + ad.w));
    *(float4*)&p1[(size_t)j * 4] = p;
}

__global__ __launch_bounds__(256) void p2_kernel(const int* __restrict__ esrc,
                                                 const int* __restrict__ edst,
                                                 const float* __restrict__ als,
                                                 const float* __restrict__ ald,
                                                 float* __restrict__ p2) {
    int j = blockIdx.x * 256 + threadIdx.x;
    if (j >= E_EDGES + N_NODES) return;
    p2[j] = __expf(lrelu(als[esrc[j]] + ald[edst[j]]));
}

// -------------------- single-pass aggregation (streamed p) --------------------

// layer 1: 1 wave per dst. 4 groups x 16 lanes; group g handles edge j0+g;
// lane li covers cols li*8..li*8+7 (head li>>2) via one 16B load.
__global__ __launch_bounds__(256) void aggr1_kernel(const int* __restrict__ row_ptr,
                                                    const int* __restrict__ esrc,
                                                    const float* __restrict__ p1,
                                                    const __bf16* __restrict__ h1b,
                                                    const float* __restrict__ b1,
                                                    float* __restrict__ h2out) {
    int wid = blockIdx.x * 4 + (threadIdx.x >> 6);
    int lane = threadIdx.x & 63;
    int grp = lane >> 4, li = lane & 15;
    int hh = li >> 2;                       // head of this lane's 8 cols
    int beg = row_ptr[wid], end = row_ptr[wid + 1];
    float acc[8] = {0,0,0,0,0,0,0,0};
    float S = 0.f;
    for (int j0 = beg; j0 < end; j0 += 4) {
        int j = j0 + grp;
        bool valid = (j < end);
        int s = valid ? esrc[j] : 0;
        float p = valid ? p1[(size_t)j * 4 + hh] : 0.f;   // streamed, CSR-contiguous
        uint4 v = *(const uint4*)(h1b + (size_t)s * HC1 + li * 8);
        acc[0] += p * bflo(v.x); acc[1] += p * bfhi(v.x);
        acc[2] += p * bflo(v.y); acc[3] += p * bfhi(v.y);
        acc[4] += p * bflo(v.z); acc[5] += p * bfhi(v.z);
        acc[6] += p * bflo(v.w); acc[7] += p * bfhi(v.w);
        S += p;
    }
    // reduce across the 4 groups (lane bits 4,5)
    #pragma unroll
    for (int d = 16; d < 64; d <<= 1) {
        #pragma unroll
        for (int c = 0; c < 8; ++c) acc[c] += __shfl_xor(acc[c], d);
        S += __shfl_xor(S, d);
    }
    if (grp == 0) {
        float inv = 1.f / S;
        const float* bp = b1 + li * 8;
        float4 o0, o1;
        o0.x = lrelu(acc[0] * inv + bp[0]);
        o0.y = lrelu(acc[1] * inv + bp[1]);
        o0.z = lrelu(acc[2] * inv + bp[2]);
        o0.w = lrelu(acc[3] * inv + bp[3]);
        o1.x = lrelu(acc[4] * inv + bp[4]);
        o1.y = lrelu(acc[5] * inv + bp[5]);
        o1.z = lrelu(acc[6] * inv + bp[6]);
        o1.w = lrelu(acc[7] * inv + bp[7]);
        float* orow = h2out + (size_t)wid * HC1 + li * 8;
        *(float4*)orow = o0;
        *(float4*)(orow + 4) = o1;
    }
}

// layer 2: 1 wave per dst; 4 groups x 16 lanes; lane li covers cols li*4..li*4+3.
__global__ __launch_bounds__(256) void aggr2_kernel(const int* __restrict__ row_ptr,
                                                    const int* __restrict__ esrc,
                                                    const float* __restrict__ p2,
                                                    const float* __restrict__ g,
                                                    const float* __restrict__ b2,
                                                    float* __restrict__ out) {
    int wid = blockIdx.x * 4 + (threadIdx.x >> 6);
    int lane = threadIdx.x & 63;
    int grp = lane >> 4, li = lane & 15;
    int beg = row_ptr[wid], end = row_ptr[wid + 1];
    float a0 = 0.f, a1 = 0.f, a2 = 0.f, a3 = 0.f, S = 0.f;
    for (int j0 = beg; j0 < end; j0 += 4) {
        int j = j0 + grp;
        bool valid = (j < end);
        int s = valid ? esrc[j] : 0;
        float p = valid ? p2[j] : 0.f;
        float4 gv = *(const float4*)(g + (size_t)s * F_OUT + li * 4);
        a0 += p * gv.x; a1 += p * gv.y; a2 += p * gv.z; a3 += p * gv.w;
        S += p;
    }
    #pragma unroll
    for (int d = 16; d < 64; d <<= 1) {
        a0 += __shfl_xor(a0, d); a1 += __shfl_xor(a1, d);
        a2 += __shfl_xor(a2, d); a3 += __shfl_xor(a3, d);
        S += __shfl_xor(S, d);
    }
    if (grp == 0) {
        float inv = 1.f / S;
        const float* bp = b2 + li * 4;
        float4 o;
        o.x = a0 * inv + bp[0];
        o.y = a1 * inv + bp[1];
        o.z = a2 * inv + bp[2];
        o.w = a3 * inv + bp[3];
        *(float4*)(out + (size_t)wid * F_OUT + li * 4) = o;
    }
}

// -------------------- launch --------------------

extern "C" void kernel_launch(void* const* d_in, const int* in_sizes, int n_in,
                              void* d_out, int out_size, void* d_ws, size_t ws_size,
                              hipStream_t stream) {
    const float* x      = (const float*)d_in[0];
    const int*   ei     = (const int*)  d_in[1];
    const float* W1     = (const float*)d_in[2];
    const float* a_src1 = (const float*)d_in[3];
    const float* a_dst1 = (const float*)d_in[4];
    const float* b1     = (const float*)d_in[5];
    const float* W2     = (const float*)d_in[6];
    const float* a_src2 = (const float*)d_in[7];
    const float* a_dst2 = (const float*)d_in[8];
    const float* b2     = (const float*)d_in[9];
    float* out = (float*)d_out;
    char* ws = (char*)d_ws;

    // workspace layout (bytes)
    __bf16* h1b  = (__bf16*)(ws + 0);           // N*128*2 = 12,800,000
    float* h2    = (float*)(ws + 12800000);     // N*128*4 = 25,600,000
    float* g     = (float*)(ws + 38400000);     // N*64*4 = 12,800,000
    float* als1  = (float*)(ws + 51200000);     // N*4*4 = 800,000
    float* ald1  = (float*)(ws + 52000000);     // 800,000
    float* als2  = (float*)(ws + 52800000);     // 200,000
    float* ald2  = (float*)(ws + 53000000);     // 200,000
    int*   rowp  = (int*)  (ws + 53200000);     // (N+1)*4
    int*   cursor= (int*)  (ws + 53400064);     // N*4
    int*   esrc  = (int*)  (ws + 53600064);     // (E+N)*4 = 2,600,000
    __bf16* whi1 = (__bf16*)(ws + 56200064);    // 65,536
    __bf16* wlo1 = (__bf16*)(ws + 56265600);    // 65,536
    __bf16* whi2 = (__bf16*)(ws + 56331136);    // 16,384
    __bf16* wlo2 = (__bf16*)(ws + 56347520);    // 16,384
    int*   bsum  = (int*)  (ws + 56363904);     // 196 B
    int*   edst  = (int*)  (ws + 56364160);     // (E+N)*4 = 2,600,000 (end 58,964,160)
    // recycled regions:
    float* p1 = g;                // 10.4MB <= 12.8MB; consumed by aggr1 before gemm2 writes g
    float* p2 = (float*)h1b;      // 2.6MB; h1b dead after aggr1

    const int TOT = E_EDGES + N_NODES;
    const int eb = (TOT + 255) / 256;

    hipMemsetAsync(cursor, 0, N_NODES * sizeof(int), stream);
    hist_kernel<<<eb, 256, 0, stream>>>(ei, cursor);
    scan1_kernel<<<SCAN_BLOCKS, 1024, 0, stream>>>(cursor, rowp, bsum);
    scan2_kernel<<<1, 64, 0, stream>>>(bsum, rowp);
    scan3_kernel<<<SCAN_BLOCKS, 1024, 0, stream>>>(rowp, bsum, cursor);
    scatter_kernel<<<eb, 256, 0, stream>>>(ei, cursor, esrc, edst);

    pack_w_kernel<F_IN, HC1><<<(F_IN * HC1 + 255) / 256, 256, 0, stream>>>(W1, whi1, wlo1);
    pack_w_kernel<HC1, F_OUT><<<(HC1 * F_OUT + 255) / 256, 256, 0, stream>>>(W2, whi2, wlo2);

    // gemm1: 128 tile-groups x 2 col-halves = 256 blocks (1/CU, one resident round)
    gemm_persist_kernel<F_IN, HC1, true, 2><<<256, 1024, 0, stream>>>(
        x, whi1, wlo1, a_src1, a_dst1, h1b, als1, ald1);
    p1_kernel<<<eb, 256, 0, stream>>>(esrc, edst, als1, ald1, p1);
    aggr1_kernel<<<N_NODES / 4, 256, 0, stream>>>(rowp, esrc, p1, h1b, b1, h2);

    // gemm2: full B (32KB) in LDS, 128 blocks
    gemm_persist_kernel<HC1, F_OUT, false, 1><<<128, 1024, 0, stream>>>(
        h2, whi2, wlo2, a_src2, a_dst2, g, als2, ald2);
    p2_kernel<<<eb, 256, 0, stream>>>(esrc, edst, als2, ald2, p2);
    aggr2_kernel<<<N_NODES / 4, 256, 0, stream>>>(rowp, esrc, p2, g, b2, out);
}

// Round 13
// 197.355 us; speedup vs baseline: 1.8929x; 1.7190x over previous
//
#include <hip/hip_runtime.h>
#include <hip/hip_bf16.h>

#define N_NODES 50000
#define E_EDGES 600000
#define F_IN    256
#define HC1     128   // 4 heads * 32
#define F_OUT   64
#define SCAN_BLOCKS 49   // ceil(N_NODES / 1024)

typedef __bf16 bf16x8 __attribute__((ext_vector_type(8)));
typedef __bf16 bf16x4 __attribute__((ext_vector_type(4)));
typedef float  f32x4  __attribute__((ext_vector_type(4)));

// -------------------- CSR build --------------------

__global__ void hist_kernel(const int* __restrict__ ei, int* __restrict__ count) {
    int i = blockIdx.x * blockDim.x + threadIdx.x;
    const int total = E_EDGES + N_NODES;
    if (i >= total) return;
    int d = (i < E_EDGES) ? ei[E_EDGES + i] : (i - E_EDGES);
    atomicAdd(&count[d], 1);
}

// hierarchical scan, phase 1: block-local exclusive scan + block totals.
__global__ __launch_bounds__(1024) void scan1_kernel(const int* __restrict__ count,
                                                     int* __restrict__ row_ptr,
                                                     int* __restrict__ bsum) {
    __shared__ int wsum[16];
    int tid = threadIdx.x, lane = tid & 63, w = tid >> 6;
    int i = blockIdx.x * 1024 + tid;
    int v = (i < N_NODES) ? count[i] : 0;
    int s = v;
    #pragma unroll
    for (int d = 1; d < 64; d <<= 1) {
        int t = __shfl_up(s, d);
        if (lane >= d) s += t;
    }
    if (lane == 63) wsum[w] = s;
    __syncthreads();
    if (tid < 16) {
        int t = wsum[tid];
        #pragma unroll
        for (int d = 1; d < 16; d <<= 1) {
            int u = __shfl_up(t, d);
            if (tid >= d) t += u;
        }
        wsum[tid] = t;
    }
    __syncthreads();
    int excl = (w ? wsum[w - 1] : 0) + s - v;
    if (i < N_NODES) row_ptr[i] = excl;
    if (tid == 0) bsum[blockIdx.x] = wsum[15];
}

// phase 2: one wave scans the 49 block totals (exclusive); writes grand total.
__global__ void scan2_kernel(int* __restrict__ bsum, int* __restrict__ row_ptr) {
    int lane = threadIdx.x;   // 64 threads
    int v = (lane < SCAN_BLOCKS) ? bsum[lane] : 0;
    int s = v;
    #pragma unroll
    for (int d = 1; d < 64; d <<= 1) {
        int t = __shfl_up(s, d);
        if (lane >= d) s += t;
    }
    if (lane < SCAN_BLOCKS) bsum[lane] = s - v;
    if (lane == 63) row_ptr[N_NODES] = s;
}

// phase 3: add block offsets; init cursor.
__global__ __launch_bounds__(1024) void scan3_kernel(int* __restrict__ row_ptr,
                                                     const int* __restrict__ bsum,
                                                     int* __restrict__ cursor) {
    int i = blockIdx.x * 1024 + threadIdx.x;
    if (i >= N_NODES) return;
    int v = row_ptr[i] + bsum[blockIdx.x];
    row_ptr[i] = v;
    cursor[i] = v;
}

__global__ void scatter_kernel(const int* __restrict__ ei, int* __restrict__ cursor,
                               int* __restrict__ esrc, int* __restrict__ edst) {
    int i = blockIdx.x * blockDim.x + threadIdx.x;
    const int total = E_EDGES + N_NODES;
    if (i >= total) return;
    int s, d;
    if (i < E_EDGES) { s = ei[i]; d = ei[E_EDGES + i]; }
    else             { s = d = i - E_EDGES; }
    int pos = atomicAdd(&cursor[d], 1);
    esrc[pos] = s;
    edst[pos] = d;
}

// -------------------- W pre-pack into MFMA B-fragment order (bf16 hi/lo) ------

template<int KDIM, int NC>
__global__ void pack_w_kernel(const float* __restrict__ W,
                              __bf16* __restrict__ hi, __bf16* __restrict__ lo) {
    constexpr int KT  = KDIM / 32;
    constexpr int LKT = (KT == 8) ? 3 : 2;
    int tid = blockIdx.x * blockDim.x + threadIdx.x;
    if (tid >= KDIM * NC) return;
    int j  = tid & 7;
    int l  = (tid >> 3) & 63;
    int kt = (tid >> 9) & (KT - 1);
    int ct = tid >> (9 + LKT);
    int k   = kt * 32 + (l >> 4) * 8 + j;
    int col = ct * 16 + (l & 15);
    float v = W[k * NC + col];
    __bf16 h = (__bf16)v;
    hi[tid] = h;
    lo[tid] = (__bf16)(v - (float)h);
}

// -------------------- LDS-A split-bf16 MFMA GEMM, 2 waves, B-reuse x2 ---------
// 128 threads = 2 waves. A-tile staged to LDS (bf16 hi/lo, padded stride).
// Each wave processes ROWT=2 row-tiles per B-fragment load: B L2 traffic
// halves vs R9, and 24 MFMAs/kt cover the ~200cy L2 latency.
// LDS ~34KB -> 4 blocks/CU = 2 waves/SIMD -> VGPR cap 256 (no spill).
// gemm1 (CGROUPS=2): wave w = col-half w, both waves share 2 row-tiles (32 rows).
// gemm2 (CGROUPS=1): wave w = row-tiles {2w,2w+1}, full cols (64 rows/block).

template<int KDIM, int NC, bool CBF16, int CGROUPS>
__global__ __launch_bounds__(128) void gemm_mfma_kernel(const float* __restrict__ A,
                                                        const __bf16* __restrict__ Whi,
                                                        const __bf16* __restrict__ Wlo,
                                                        const float* __restrict__ a_s,
                                                        const float* __restrict__ a_d,
                                                        void* __restrict__ Cout,
                                                        float* __restrict__ als,
                                                        float* __restrict__ ald) {
    constexpr int KT   = KDIM / 32;
    constexpr int CT   = NC / 16;
    constexpr int CTW  = CT / CGROUPS;     // col tiles per wave (4)
    constexpr int ROWT = 2;                // row-tiles per wave
    constexpr int RTPB = (CGROUPS == 2) ? ROWT : 2 * ROWT;   // row-tiles per block
    constexpr int RPB  = RTPB * 16;        // rows per block: 32 or 64
    constexpr int LSTR = KDIM + 8;         // bf16 row stride: 16B-aligned, ~2-way banks
    constexpr int F4PR = KDIM / 4;
    __shared__ __bf16 ah[RPB][LSTR];
    __shared__ __bf16 al[RPB][LSTR];

    int tid = threadIdx.x;

    // ---- cooperative stage: coalesced float4 loads, convert once, LDS write ----
    #pragma unroll
    for (int it = 0; it < (RPB * F4PR) / 128; ++it) {
        int idx = it * 128 + tid;
        int row = idx / F4PR;
        int kk  = (idx - row * F4PR) * 4;
        int grow = blockIdx.x * RPB + row;
        const float* src = A + (size_t)(grow < N_NODES ? grow : N_NODES - 1) * KDIM + kk;
        float4 v = *(const float4*)src;
        bf16x4 h, lo;
        h[0] = (__bf16)v.x; h[1] = (__bf16)v.y; h[2] = (__bf16)v.z; h[3] = (__bf16)v.w;
        lo[0] = (__bf16)(v.x - (float)h[0]);
        lo[1] = (__bf16)(v.y - (float)h[1]);
        lo[2] = (__bf16)(v.z - (float)h[2]);
        lo[3] = (__bf16)(v.w - (float)h[3]);
        *(bf16x4*)&ah[row][kk] = h;
        *(bf16x4*)&al[row][kk] = lo;
    }
    __syncthreads();

    int w = tid >> 6, l = tid & 63;
    int cg = (CGROUPS == 2) ? w : 0;
    int c0 = cg * CTW;
    int t0 = (CGROUPS == 2) ? 0 : w * ROWT;   // first row-tile of this wave
    int koff = (l >> 4) * 8;
    int ccol = l & 15;

    int rowL[ROWT];
    #pragma unroll
    for (int t = 0; t < ROWT; ++t) rowL[t] = (t0 + t) * 16 + (l & 15);

    // B double-buffer (explicit, compile-time indexed after unroll)
    bf16x8 bh[2][CTW], bl[2][CTW];
    #pragma unroll
    for (int c = 0; c < CTW; ++c) {
        size_t bidx = ((size_t)((c0 + c) * KT + 0) * 64 + l) * 8;
        bh[0][c] = *(const bf16x8*)(Whi + bidx);
        bl[0][c] = *(const bf16x8*)(Wlo + bidx);
    }

    f32x4 acc[ROWT][CTW];
    #pragma unroll
    for (int t = 0; t < ROWT; ++t)
        #pragma unroll
        for (int c = 0; c < CTW; ++c) acc[t][c] = (f32x4){0.f, 0.f, 0.f, 0.f};

    #pragma unroll
    for (int kt = 0; kt < KT; ++kt) {
        const int cur = kt & 1, nxt = cur ^ 1;
        if (kt + 1 < KT) {
            #pragma unroll
            for (int c = 0; c < CTW; ++c) {
                size_t bidx = ((size_t)((c0 + c) * KT + (kt + 1)) * 64 + l) * 8;
                bh[nxt][c] = *(const bf16x8*)(Whi + bidx);
                bl[nxt][c] = *(const bf16x8*)(Wlo + bidx);
            }
        }
        #pragma unroll
        for (int t = 0; t < ROWT; ++t) {
            bf16x8 ahi = *(const bf16x8*)&ah[rowL[t]][kt * 32 + koff];
            bf16x8 alo = *(const bf16x8*)&al[rowL[t]][kt * 32 + koff];
            #pragma unroll
            for (int c = 0; c < CTW; ++c) {
                acc[t][c] = __builtin_amdgcn_mfma_f32_16x16x32_bf16(ahi, bh[cur][c], acc[t][c], 0, 0, 0);
                acc[t][c] = __builtin_amdgcn_mfma_f32_16x16x32_bf16(ahi, bl[cur][c], acc[t][c], 0, 0, 0);
                acc[t][c] = __builtin_amdgcn_mfma_f32_16x16x32_bf16(alo, bh[cur][c], acc[t][c], 0, 0, 0);
            }
        }
    }

    float as_c[CTW], ad_c[CTW];
    #pragma unroll
    for (int c = 0; c < CTW; ++c) {
        as_c[c] = a_s[(c0 + c) * 16 + ccol];
        ad_c[c] = a_d[(c0 + c) * 16 + ccol];
    }

    #pragma unroll
    for (int t = 0; t < ROWT; ++t) {
        int crow0 = blockIdx.x * RPB + (t0 + t) * 16 + (l >> 4) * 4;

        // C store
        #pragma unroll
        for (int c = 0; c < CTW; ++c) {
            #pragma unroll
            for (int r = 0; r < 4; ++r) {
                int row = crow0 + r;
                if (row < N_NODES) {
                    if constexpr (CBF16)
                        ((__bf16*)Cout)[(size_t)row * NC + (c0 + c) * 16 + ccol] = (__bf16)acc[t][c][r];
                    else
                        ((float*)Cout)[(size_t)row * NC + (c0 + c) * 16 + ccol] = acc[t][c][r];
                }
            }
        }

        // fused attention scalars (wave-local reductions over the 16 ccol lanes)
        #pragma unroll
        for (int r = 0; r < 4; ++r) {
            int row = crow0 + r;
            if constexpr (NC == 128) {
                // CTW=4: this wave's col-half holds 2 whole heads
                #pragma unroll
                for (int hl = 0; hl < 2; ++hl) {
                    int h = cg * 2 + hl;
                    float vs = acc[t][2 * hl][r] * as_c[2 * hl] + acc[t][2 * hl + 1][r] * as_c[2 * hl + 1];
                    float vd = acc[t][2 * hl][r] * ad_c[2 * hl] + acc[t][2 * hl + 1][r] * ad_c[2 * hl + 1];
                    #pragma unroll
                    for (int d = 1; d < 16; d <<= 1) {
                        vs += __shfl_xor(vs, d);
                        vd += __shfl_xor(vd, d);
                    }
                    if (ccol == 0 && row < N_NODES) { als[row * 4 + h] = vs; ald[row * 4 + h] = vd; }
                }
            } else {
                float vs = 0.f, vd = 0.f;
                #pragma unroll
                for (int c = 0; c < CTW; ++c) { vs += acc[t][c][r] * as_c[c]; vd += acc[t][c][r] * ad_c[c]; }
                #pragma unroll
                for (int d = 1; d < 16; d <<= 1) {
                    vs += __shfl_xor(vs, d);
                    vd += __shfl_xor(vd, d);
                }
                if (ccol == 0 && row < N_NODES) { als[row] = vs; ald[row] = vd; }
            }
        }
    }
}

__device__ __forceinline__ float lrelu(float x) { return x > 0.f ? x : 0.2f * x; }
__device__ __forceinline__ float bfhi(unsigned v) { return __uint_as_float(v & 0xffff0000u); }
__device__ __forceinline__ float bflo(unsigned v) { return __uint_as_float(v << 16); }

// -------------------- per-edge attention weights (unnormalized) --------------------

__global__ __launch_bounds__(256) void p1_kernel(const int* __restrict__ esrc,
                                                 const int* __restrict__ edst,
                                                 const float* __restrict__ als,
                                                 const float* __restrict__ ald,
                                                 float* __restrict__ p1) {
    int j = blockIdx.x * 256 + threadIdx.x;
    if (j >= E_EDGES + N_NODES) return;
    int s = esrc[j], d = edst[j];
    float4 as = *(const float4*)&als[s * 4];
    float4 ad = *(const float4*)&ald[d * 4];
    float4 p;
    p.x = __expf(lrelu(as.x + ad.x));
    p.y = __expf(lrelu(as.y + ad.y));
    p.z = __expf(lrelu(as.z + ad.z));
    p.w = __expf(lrelu(as.w + ad.w));
    *(float4*)&p1[(size_t)j * 4] = p;
}

__global__ __launch_bounds__(256) void p2_kernel(const int* __restrict__ esrc,
                                                 const int* __restrict__ edst,
                                                 const float* __restrict__ als,
                                                 const float* __restrict__ ald,
                                                 float* __restrict__ p2) {
    int j = blockIdx.x * 256 + threadIdx.x;
    if (j >= E_EDGES + N_NODES) return;
    p2[j] = __expf(lrelu(als[esrc[j]] + ald[edst[j]]));
}

// -------------------- single-pass aggregation (streamed p) --------------------

// layer 1: 1 wave per dst. 4 groups x 16 lanes; group g handles edge j0+g;
// lane li covers cols li*8..li*8+7 (head li>>2) via one 16B load.
__global__ __launch_bounds__(256) void aggr1_kernel(const int* __restrict__ row_ptr,
                                                    const int* __restrict__ esrc,
                                                    const float* __restrict__ p1,
                                                    const __bf16* __restrict__ h1b,
                                                    const float* __restrict__ b1,
                                                    float* __restrict__ h2out) {
    int wid = blockIdx.x * 4 + (threadIdx.x >> 6);
    int lane = threadIdx.x & 63;
    int grp = lane >> 4, li = lane & 15;
    int hh = li >> 2;                       // head of this lane's 8 cols
    int beg = row_ptr[wid], end = row_ptr[wid + 1];
    float acc[8] = {0,0,0,0,0,0,0,0};
    float S = 0.f;
    for (int j0 = beg; j0 < end; j0 += 4) {
        int j = j0 + grp;
        bool valid = (j < end);
        int s = valid ? esrc[j] : 0;
        float p = valid ? p1[(size_t)j * 4 + hh] : 0.f;   // streamed, CSR-contiguous
        uint4 v = *(const uint4*)(h1b + (size_t)s * HC1 + li * 8);
        acc[0] += p * bflo(v.x); acc[1] += p * bfhi(v.x);
        acc[2] += p * bflo(v.y); acc[3] += p * bfhi(v.y);
        acc[4] += p * bflo(v.z); acc[5] += p * bfhi(v.z);
        acc[6] += p * bflo(v.w); acc[7] += p * bfhi(v.w);
        S += p;
    }
    // reduce across the 4 groups (lane bits 4,5)
    #pragma unroll
    for (int d = 16; d < 64; d <<= 1) {
        #pragma unroll
        for (int c = 0; c < 8; ++c) acc[c] += __shfl_xor(acc[c], d);
        S += __shfl_xor(S, d);
    }
    if (grp == 0) {
        float inv = 1.f / S;
        const float* bp = b1 + li * 8;
        float4 o0, o1;
        o0.x = lrelu(acc[0] * inv + bp[0]);
        o0.y = lrelu(acc[1] * inv + bp[1]);
        o0.z = lrelu(acc[2] * inv + bp[2]);
        o0.w = lrelu(acc[3] * inv + bp[3]);
        o1.x = lrelu(acc[4] * inv + bp[4]);
        o1.y = lrelu(acc[5] * inv + bp[5]);
        o1.z = lrelu(acc[6] * inv + bp[6]);
        o1.w = lrelu(acc[7] * inv + bp[7]);
        float* orow = h2out + (size_t)wid * HC1 + li * 8;
        *(float4*)orow = o0;
        *(float4*)(orow + 4) = o1;
    }
}

// layer 2: 1 wave per dst; 4 groups x 16 lanes; lane li covers cols li*4..li*4+3.
__global__ __launch_bounds__(256) void aggr2_kernel(const int* __restrict__ row_ptr,
                                                    const int* __restrict__ esrc,
                                                    const float* __restrict__ p2,
                                                    const float* __restrict__ g,
                                                    const float* __restrict__ b2,
                                                    float* __restrict__ out) {
    int wid = blockIdx.x * 4 + (threadIdx.x >> 6);
    int lane = threadIdx.x & 63;
    int grp = lane >> 4, li = lane & 15;
    int beg = row_ptr[wid], end = row_ptr[wid + 1];
    float a0 = 0.f, a1 = 0.f, a2 = 0.f, a3 = 0.f, S = 0.f;
    for (int j0 = beg; j0 < end; j0 += 4) {
        int j = j0 + grp;
        bool valid = (j < end);
        int s = valid ? esrc[j] : 0;
        float p = valid ? p2[j] : 0.f;
        float4 gv = *(const float4*)(g + (size_t)s * F_OUT + li * 4);
        a0 += p * gv.x; a1 += p * gv.y; a2 += p * gv.z; a3 += p * gv.w;
        S += p;
    }
    #pragma unroll
    for (int d = 16; d < 64; d <<= 1) {
        a0 += __shfl_xor(a0, d); a1 += __shfl_xor(a1, d);
        a2 += __shfl_xor(a2, d); a3 += __shfl_xor(a3, d);
        S += __shfl_xor(S, d);
    }
    if (grp == 0) {
        float inv = 1.f / S;
        const float* bp = b2 + li * 4;
        float4 o;
        o.x = a0 * inv + bp[0];
        o.y = a1 * inv + bp[1];
        o.z = a2 * inv + bp[2];
        o.w = a3 * inv + bp[3];
        *(float4*)(out + (size_t)wid * F_OUT + li * 4) = o;
    }
}

// -------------------- launch --------------------

extern "C" void kernel_launch(void* const* d_in, const int* in_sizes, int n_in,
                              void* d_out, int out_size, void* d_ws, size_t ws_size,
                              hipStream_t stream) {
    const float* x      = (const float*)d_in[0];
    const int*   ei     = (const int*)  d_in[1];
    const float* W1     = (const float*)d_in[2];
    const float* a_src1 = (const float*)d_in[3];
    const float* a_dst1 = (const float*)d_in[4];
    const float* b1     = (const float*)d_in[5];
    const float* W2     = (const float*)d_in[6];
    const float* a_src2 = (const float*)d_in[7];
    const float* a_dst2 = (const float*)d_in[8];
    const float* b2     = (const float*)d_in[9];
    float* out = (float*)d_out;
    char* ws = (char*)d_ws;

    // workspace layout (bytes)
    __bf16* h1b  = (__bf16*)(ws + 0);           // N*128*2 = 12,800,000
    float* h2    = (float*)(ws + 12800000);     // N*128*4 = 25,600,000
    float* g     = (float*)(ws + 38400000);     // N*64*4 = 12,800,000
    float* als1  = (float*)(ws + 51200000);     // N*4*4 = 800,000
    float* ald1  = (float*)(ws + 52000000);     // 800,000
    float* als2  = (float*)(ws + 52800000);     // 200,000
    float* ald2  = (float*)(ws + 53000000);     // 200,000
    int*   rowp  = (int*)  (ws + 53200000);     // (N+1)*4
    int*   cursor= (int*)  (ws + 53400064);     // N*4
    int*   esrc  = (int*)  (ws + 53600064);     // (E+N)*4 = 2,600,000
    __bf16* whi1 = (__bf16*)(ws + 56200064);    // 65,536
    __bf16* wlo1 = (__bf16*)(ws + 56265600);    // 65,536
    __bf16* whi2 = (__bf16*)(ws + 56331136);    // 16,384
    __bf16* wlo2 = (__bf16*)(ws + 56347520);    // 16,384
    int*   bsum  = (int*)  (ws + 56363904);     // 196 B
    int*   edst  = (int*)  (ws + 56364160);     // (E+N)*4 = 2,600,000 (end 58,964,160)
    // recycled regions:
    float* p1 = g;                // 10.4MB <= 12.8MB; consumed by aggr1 before gemm2 writes g
    float* p2 = (float*)h1b;      // 2.6MB; h1b dead after aggr1

    const int TOT = E_EDGES + N_NODES;
    const int eb = (TOT + 255) / 256;

    hipMemsetAsync(cursor, 0, N_NODES * sizeof(int), stream);
    hist_kernel<<<eb, 256, 0, stream>>>(ei, cursor);
    scan1_kernel<<<SCAN_BLOCKS, 1024, 0, stream>>>(cursor, rowp, bsum);
    scan2_kernel<<<1, 64, 0, stream>>>(bsum, rowp);
    scan3_kernel<<<SCAN_BLOCKS, 1024, 0, stream>>>(rowp, bsum, cursor);
    scatter_kernel<<<eb, 256, 0, stream>>>(ei, cursor, esrc, edst);

    pack_w_kernel<F_IN, HC1><<<(F_IN * HC1 + 255) / 256, 256, 0, stream>>>(W1, whi1, wlo1);
    pack_w_kernel<HC1, F_OUT><<<(HC1 * F_OUT + 255) / 256, 256, 0, stream>>>(W2, whi2, wlo2);

    // gemm1: 32 rows/block, 2 waves (col-halves), ROWT=2 -> 1563 blocks
    gemm_mfma_kernel<F_IN, HC1, true, 2><<<(N_NODES + 31) / 32, 128, 0, stream>>>(
        x, whi1, wlo1, a_src1, a_dst1, h1b, als1, ald1);
    p1_kernel<<<eb, 256, 0, stream>>>(esrc, edst, als1, ald1, p1);
    aggr1_kernel<<<N_NODES / 4, 256, 0, stream>>>(rowp, esrc, p1, h1b, b1, h2);

    // gemm2: 64 rows/block, 2 waves (row-tile pairs), ROWT=2 -> 782 blocks
    gemm_mfma_kernel<HC1, F_OUT, false, 1><<<(N_NODES + 63) / 64, 128, 0, stream>>>(
        h2, whi2, wlo2, a_src2, a_dst2, g, als2, ald2);
    p2_kernel<<<eb, 256, 0, stream>>>(esrc, edst, als2, ald2, p2);
    aggr2_kernel<<<N_NODES / 4, 256, 0, stream>>>(rowp, esrc, p2, g, b2, out);
}